// Round 6
// baseline (666.511 us; speedup 1.0000x reference)
//
#include <hip/hip_runtime.h>
#include <cmath>

#define N_NODES 100000
#define N_EDGES 1600000
#define F_IN 512
#define F_HID 128
#define F_OUT 64

#define SCAN_NB ((N_NODES + 255) / 256)   // 391 blocks

// ---- bucketed CSR-build params ----
#define BK_SHIFT 10                        // 1024 nodes per bucket
#define NBUK ((N_NODES + 1023) >> 10)      // 98 buckets
#define SCAP 24576                         // staging capacity/bucket
#define LSLOT 64                           // LDS slots per bucket
#define NBLK_A 128                         // partition blocks
#define OV_CAP 4096                        // global overflow records

typedef __attribute__((ext_vector_type(8))) short short8;
typedef __attribute__((ext_vector_type(4))) float float4v;

__device__ __forceinline__ unsigned short f2bf(float f) {
    unsigned u = __builtin_bit_cast(unsigned, f);
    u += 0x7FFFu + ((u >> 16) & 1u);   // RNE
    return (unsigned short)(u >> 16);
}
__device__ __forceinline__ float bf2f(unsigned short s) {
    unsigned u = ((unsigned)s) << 16;
    return __builtin_bit_cast(float, u);
}
__device__ __forceinline__ float lo_bf(unsigned u) {
    return __builtin_bit_cast(float, u << 16);
}
__device__ __forceinline__ float hi_bf(unsigned u) {
    return __builtin_bit_cast(float, u & 0xFFFF0000u);
}
__device__ __forceinline__ short8 cvt8(float4 a, float4 b) {
    return short8{(short)f2bf(a.x), (short)f2bf(a.y), (short)f2bf(a.z), (short)f2bf(a.w),
                  (short)f2bf(b.x), (short)f2bf(b.y), (short)f2bf(b.z), (short)f2bf(b.w)};
}

// ---------------- partition: edges -> per-bucket staging (+deg count fused) ----------------
__global__ __launch_bounds__(256) void partition_kernel(
    const int* __restrict__ src, const int* __restrict__ dst,
    int* __restrict__ deg, unsigned* __restrict__ staging, int* __restrict__ gcur,
    unsigned long long* __restrict__ ovbuf, int* __restrict__ ovcnt) {
    __shared__ unsigned buf[NBUK][LSLOT];
    __shared__ int cnt[NBUK];
    int tid = threadIdx.x;
    for (int b = tid; b < NBUK; b += 256) cnt[b] = 0;
    __syncthreads();
    const int PER = (N_EDGES + NBLK_A - 1) / NBLK_A;   // 12500
    int e0 = blockIdx.x * PER;
    int e1 = min(e0 + PER, N_EDGES);
    for (int base = e0; base < e1; base += 1024) {
#pragma unroll
        for (int t = 0; t < 4; ++t) {
            int e = base + t * 256 + tid;
            if (e < e1) {
                int d = dst[e];
                int s = src[e];
                atomicAdd(&deg[d], 1);
                int b = d >> BK_SHIFT;
                unsigned rec = (unsigned)s | ((unsigned)(d & 1023) << 17);
                int slot = atomicAdd(&cnt[b], 1);
                if (slot < LSLOT) {
                    buf[b][slot] = rec;
                } else {
                    int op = atomicAdd(ovcnt, 1);
                    if (op < OV_CAP)
                        ovbuf[op] = ((unsigned long long)(unsigned)d << 32) | (unsigned)s;
                }
            }
        }
        __syncthreads();
        for (int b = tid; b < NBUK; b += 256) {
            int c = min(cnt[b], LSLOT);
            int full = c & ~15;
            if (full > 0) {
                int pos = atomicAdd(&gcur[b], full);
                if (pos + full <= SCAP) {
                    unsigned* dp = &staging[(size_t)b * SCAP + pos];
                    for (int i = 0; i < full; ++i) dp[i] = buf[b][i];
                }
                for (int i = 0; i < c - full; ++i) buf[b][i] = buf[b][full + i];
            }
            cnt[b] = c - full;
        }
        __syncthreads();
    }
    for (int b = tid; b < NBUK; b += 256) {
        int c = cnt[b];
        if (c > 0) {
            int pos = atomicAdd(&gcur[b], c);
            if (pos + c <= SCAP)
                for (int i = 0; i < c; ++i) staging[(size_t)b * SCAP + pos + i] = buf[b][i];
        }
    }
}

// ---------------- fill: one block per bucket ----------------
__global__ __launch_bounds__(256) void fill_kernel(
    const unsigned* __restrict__ staging, const int* __restrict__ gcur,
    int* __restrict__ cursor, int* __restrict__ csr_src,
    const unsigned long long* __restrict__ ovbuf, const int* __restrict__ ovcnt) {
    int b = blockIdx.x;
    int node0 = b << BK_SHIFT;
    int n = gcur[b];
    if (n > SCAP) n = SCAP;
    const unsigned* sp = &staging[(size_t)b * SCAP];
    for (int i = threadIdx.x; i < n; i += 256) {
        unsigned rec = sp[i];
        int s = (int)(rec & 0x1FFFFu);
        int d = node0 + (int)(rec >> 17);
        int pos = atomicAdd(&cursor[d], 1);
        csr_src[pos] = s;
    }
    int oc = *ovcnt;
    if (oc > OV_CAP) oc = OV_CAP;
    for (int i = threadIdx.x; i < oc; i += 256) {
        unsigned long long r = ovbuf[i];
        int d = (int)(r >> 32);
        if ((d >> BK_SHIFT) == b) {
            int pos = atomicAdd(&cursor[d], 1);
            csr_src[pos] = (int)(r & 0xffffffffu);
        }
    }
}

// ---------------- scans ----------------

__global__ __launch_bounds__(256) void block_sum_kernel(const int* __restrict__ deg,
                                                        int* __restrict__ bsum, int n) {
    int g = blockIdx.x * 256 + threadIdx.x;
    int v = (g < n) ? deg[g] : 0;
    __shared__ int ws[4];
    int lane = threadIdx.x & 63;
    int w = threadIdx.x >> 6;
#pragma unroll
    for (int o = 32; o > 0; o >>= 1) v += __shfl_down(v, o, 64);
    if (lane == 0) ws[w] = v;
    __syncthreads();
    if (threadIdx.x == 0) bsum[blockIdx.x] = ws[0] + ws[1] + ws[2] + ws[3];
}

__global__ __launch_bounds__(512) void scan_partials_kernel(int* __restrict__ bsum, int nb) {
    __shared__ int t[512];
    int tid = threadIdx.x;
    int v = (tid < nb) ? bsum[tid] : 0;
    t[tid] = v;
    __syncthreads();
    for (int d = 1; d < 512; d <<= 1) {
        int u = (tid >= d) ? t[tid - d] : 0;
        __syncthreads();
        t[tid] += u;
        __syncthreads();
    }
    if (tid < nb) bsum[tid] = t[tid] - v;  // exclusive
}

__global__ __launch_bounds__(256) void scan_final_kernel(const int* __restrict__ deg,
                                                         const int* __restrict__ bsum,
                                                         int* __restrict__ row_ptr,
                                                         int* __restrict__ cursor,
                                                         float* __restrict__ dinv, int n) {
    __shared__ int t[256];
    int g = blockIdx.x * 256 + threadIdx.x;
    int tid = threadIdx.x;
    int v = (g < n) ? deg[g] : 0;
    t[tid] = v;
    __syncthreads();
    for (int d = 1; d < 256; d <<= 1) {
        int u = (tid >= d) ? t[tid - d] : 0;
        __syncthreads();
        t[tid] += u;
        __syncthreads();
    }
    int off = bsum[blockIdx.x] + t[tid] - v;
    if (g < n) {
        row_ptr[g] = off;
        cursor[g] = off;
        dinv[g] = rsqrtf((float)(v + 1));
    }
    if (g == n - 1) row_ptr[n] = off + v;
}

// ---------------- W transpose+convert: Wt[n][k] bf16 ----------------

__global__ void transpose_w_kernel(const float* __restrict__ W1, const float* __restrict__ W2,
                                   unsigned short* __restrict__ Wt1,
                                   unsigned short* __restrict__ Wt2) {
    int g = blockIdx.x * 256 + threadIdx.x;
    if (g < F_HID * F_IN) {               // Wt1: [128][512]
        int n = g >> 9, k = g & 511;
        Wt1[g] = f2bf(W1[k * F_HID + n]);
    } else {
        int h = g - F_HID * F_IN;         // Wt2: [64][128]
        if (h < F_OUT * F_HID) {
            int n = h >> 7, k = h & 127;
            Wt2[h] = f2bf(W2[k * F_OUT + n]);
        }
    }
}

// ---------------- pipelined barrier-free MFMA GEMM ----------------
// R5 post-mortem: VGPR=92 left ~zero regs for in-flight loads -> fully
// serialized latency (~1 load/CU in flight). Fix: __launch_bounds__(256,2)
// (VGPR cap 256) + register triple-buffer; raw bytes staged, fp32->bf16
// conversion deferred to consumption so loads for it+1..it+3 stay in flight.

template <int BN, int K, bool A_BF16>
__global__ __launch_bounds__(256, 2) void gemm_direct_kernel(
    const void* __restrict__ Araw, const unsigned short* __restrict__ Wt,
    const float* __restrict__ dinv, unsigned short* __restrict__ out, int N) {
    constexpr int NI = K / 32;     // k-iterations
    constexpr int CT = BN / 16;    // column tiles
    constexpr int D = (NI < 3) ? NI : 3;   // pipeline depth
    int lane = threadIdx.x & 63;
    int wv = threadIdx.x >> 6;
    int row0 = blockIdx.x * 128 + wv * 32;
    if (row0 >= N) return;                 // no barriers in kernel: safe
    int l15 = lane & 15;
    int q = lane >> 4;
    int q8 = q * 8;
    int r0c = min(row0 + l15, N - 1);
    int r1c = min(row0 + 16 + l15, N - 1);

    // rotating register buffers (fully unrolled -> constant indices -> stay in VGPRs)
    float4 fx0[D], fx1[D], fy0[D], fy1[D];   // !A_BF16 raw
    short8 sa0[D], sa1[D];                   // A_BF16 raw
    short8 bb[D][CT];

#define LOADIT(it, s)                                                                  \
    do {                                                                               \
        int k0 = (it) * 32;                                                            \
        if (A_BF16) {                                                                  \
            const unsigned short* A = (const unsigned short*)Araw;                     \
            sa0[s] = *(const short8*)&A[(size_t)r0c * K + k0 + q8];                    \
            sa1[s] = *(const short8*)&A[(size_t)r1c * K + k0 + q8];                    \
        } else {                                                                       \
            const float* A = (const float*)Araw;                                       \
            fx0[s] = *(const float4*)&A[(size_t)r0c * K + k0 + q8];                    \
            fx1[s] = *(const float4*)&A[(size_t)r0c * K + k0 + q8 + 4];                \
            fy0[s] = *(const float4*)&A[(size_t)r1c * K + k0 + q8];                    \
            fy1[s] = *(const float4*)&A[(size_t)r1c * K + k0 + q8 + 4];                \
        }                                                                              \
        _Pragma("unroll") for (int ct = 0; ct < CT; ++ct)                              \
            bb[s][ct] = *(const short8*)&Wt[(size_t)(ct * 16 + l15) * K + k0 + q8];    \
    } while (0)

#pragma unroll
    for (int p = 0; p < D; ++p) LOADIT(p, p);

    float4v acc[2][CT] = {};

#pragma unroll
    for (int it = 0; it < NI; ++it) {
        int s = it % D;
        short8 a0, a1;
        if (A_BF16) {
            a0 = sa0[s];
            a1 = sa1[s];
        } else {
            a0 = cvt8(fx0[s], fx1[s]);
            a1 = cvt8(fy0[s], fy1[s]);
        }
#pragma unroll
        for (int ct = 0; ct < CT; ++ct) {
            acc[0][ct] = __builtin_amdgcn_mfma_f32_16x16x32_bf16(a0, bb[s][ct], acc[0][ct], 0, 0, 0);
            acc[1][ct] = __builtin_amdgcn_mfma_f32_16x16x32_bf16(a1, bb[s][ct], acc[1][ct], 0, 0, 0);
        }
        if (it + D < NI) LOADIT(it + D, s);
    }
#undef LOADIT

    // epilogue: C/D layout col=lane&15, row=q*4+reg; scale by dinv, store bf16
#pragma unroll
    for (int rt = 0; rt < 2; ++rt) {
#pragma unroll
        for (int reg = 0; reg < 4; ++reg) {
            int row = row0 + rt * 16 + q * 4 + reg;
            if (row < N) {
                float sc = dinv[row];
#pragma unroll
                for (int ct = 0; ct < CT; ++ct) {
                    out[(size_t)row * BN + ct * 16 + l15] = f2bf(acc[rt][ct][reg] * sc);
                }
            }
        }
    }
}

// ---------------- aggregation (bf16 in, fp32 accumulate) ----------------
__global__ __launch_bounds__(256) void agg1_kernel(
    const unsigned int* __restrict__ g1, const int* __restrict__ row_ptr,
    const int* __restrict__ csr_src, const float* __restrict__ dinv,
    const float* __restrict__ b1, unsigned int* __restrict__ h1) {
    int node = blockIdx.x * 4 + (threadIdx.x >> 6);
    int lane = threadIdx.x & 63;
    if (node >= N_NODES) return;
    unsigned u = g1[(size_t)node * 64 + lane];
    float a0 = lo_bf(u), a1 = hi_bf(u);
    int e = row_ptr[node], end = row_ptr[node + 1];
    for (; e + 4 <= end; e += 4) {
        int j0 = csr_src[e], j1 = csr_src[e + 1], j2 = csr_src[e + 2], j3 = csr_src[e + 3];
        unsigned u0 = g1[(size_t)j0 * 64 + lane];
        unsigned u1 = g1[(size_t)j1 * 64 + lane];
        unsigned u2 = g1[(size_t)j2 * 64 + lane];
        unsigned u3 = g1[(size_t)j3 * 64 + lane];
        a0 += lo_bf(u0) + lo_bf(u1) + lo_bf(u2) + lo_bf(u3);
        a1 += hi_bf(u0) + hi_bf(u1) + hi_bf(u2) + hi_bf(u3);
    }
    for (; e < end; ++e) {
        unsigned u0 = g1[(size_t)csr_src[e] * 64 + lane];
        a0 += lo_bf(u0);
        a1 += hi_bf(u0);
    }
    float d = dinv[node];
    float v0 = fmaxf(d * a0 + b1[2 * lane], 0.0f);
    float v1 = fmaxf(d * a1 + b1[2 * lane + 1], 0.0f);
    h1[(size_t)node * 64 + lane] = (unsigned)f2bf(v0) | ((unsigned)f2bf(v1) << 16);
}

__global__ __launch_bounds__(256) void agg2_lsm_kernel(
    const unsigned short* __restrict__ g2, const int* __restrict__ row_ptr,
    const int* __restrict__ csr_src, const float* __restrict__ dinv,
    const float* __restrict__ b2, float* __restrict__ out) {
    int node = blockIdx.x * 4 + (threadIdx.x >> 6);
    int lane = threadIdx.x & 63;
    if (node >= N_NODES) return;
    float a = bf2f(g2[(size_t)node * 64 + lane]);
    int e = row_ptr[node], end = row_ptr[node + 1];
    for (; e + 4 <= end; e += 4) {
        int j0 = csr_src[e], j1 = csr_src[e + 1], j2 = csr_src[e + 2], j3 = csr_src[e + 3];
        a += bf2f(g2[(size_t)j0 * 64 + lane]) + bf2f(g2[(size_t)j1 * 64 + lane]) +
             bf2f(g2[(size_t)j2 * 64 + lane]) + bf2f(g2[(size_t)j3 * 64 + lane]);
    }
    for (; e < end; ++e) a += bf2f(g2[(size_t)csr_src[e] * 64 + lane]);
    float v = dinv[node] * a + b2[lane];
    float m = v;
#pragma unroll
    for (int o = 32; o > 0; o >>= 1) m = fmaxf(m, __shfl_xor(m, o, 64));
    float ex = __expf(v - m);
    float s = ex;
#pragma unroll
    for (int o = 32; o > 0; o >>= 1) s += __shfl_xor(s, o, 64);
    out[(size_t)node * 64 + lane] = v - m - __logf(s);
}

// ---------------- launch ----------------

extern "C" void kernel_launch(void* const* d_in, const int* in_sizes, int n_in,
                              void* d_out, int out_size, void* d_ws, size_t ws_size,
                              hipStream_t stream) {
    const float* x  = (const float*)d_in[0];
    const int* eidx = (const int*)d_in[1];
    const float* W1 = (const float*)d_in[2];
    const float* b1 = (const float*)d_in[3];
    const float* W2 = (const float*)d_in[4];
    const float* b2 = (const float*)d_in[5];
    float* out = (float*)d_out;
    const int* src = eidx;
    const int* dst = eidx + N_EDGES;

    char* base = (char*)d_ws;
    size_t off = 0;
    auto alloc = [&](size_t bytes) -> void* {
        void* p = base + off;
        off += (bytes + 255) & ~(size_t)255;
        return p;
    };
    int* zbase    = (int*)alloc((size_t)(N_NODES + NBUK + 64) * 4);
    int* deg      = zbase;
    int* gcur     = zbase + N_NODES;
    int* ovcnt    = zbase + N_NODES + NBUK;
    int* row_ptr  = (int*)alloc((size_t)(N_NODES + 1) * 4);
    int* cursor   = (int*)alloc((size_t)N_NODES * 4);
    float* dinv   = (float*)alloc((size_t)N_NODES * 4);
    int* bsum     = (int*)alloc((size_t)SCAN_NB * 4);
    unsigned* staging = (unsigned*)alloc((size_t)NBUK * SCAP * 4);   // 9.6 MB
    unsigned long long* ovbuf = (unsigned long long*)alloc((size_t)OV_CAP * 8);
    int* csr_src  = (int*)alloc((size_t)N_EDGES * 4);
    unsigned short* Wt1 = (unsigned short*)alloc((size_t)F_HID * F_IN * 2);
    unsigned short* Wt2 = (unsigned short*)alloc((size_t)F_OUT * F_HID * 2);
    unsigned short* g1  = (unsigned short*)alloc((size_t)N_NODES * F_HID * 2);
    unsigned short* h1  = (unsigned short*)alloc((size_t)N_NODES * F_HID * 2);
    unsigned short* g2  = g1;  // g1 dead after agg1

    hipMemsetAsync(zbase, 0, (size_t)(N_NODES + NBUK + 64) * 4, stream);
    partition_kernel<<<NBLK_A, 256, 0, stream>>>(src, dst, deg, staging, gcur, ovbuf, ovcnt);
    block_sum_kernel<<<SCAN_NB, 256, 0, stream>>>(deg, bsum, N_NODES);
    scan_partials_kernel<<<1, 512, 0, stream>>>(bsum, SCAN_NB);
    scan_final_kernel<<<SCAN_NB, 256, 0, stream>>>(deg, bsum, row_ptr, cursor, dinv, N_NODES);
    fill_kernel<<<NBUK, 256, 0, stream>>>(staging, gcur, cursor, csr_src, ovbuf, ovcnt);
    transpose_w_kernel<<<(F_HID * F_IN + F_OUT * F_HID + 255) / 256, 256, 0, stream>>>(
        W1, W2, Wt1, Wt2);

    int gblocks = (N_NODES + 127) / 128;  // 782
    gemm_direct_kernel<F_HID, F_IN, false><<<gblocks, 256, 0, stream>>>(
        (const void*)x, Wt1, dinv, g1, N_NODES);
    agg1_kernel<<<(N_NODES + 3) / 4, 256, 0, stream>>>(
        (const unsigned int*)g1, row_ptr, csr_src, dinv, b1, (unsigned int*)h1);

    gemm_direct_kernel<F_OUT, F_HID, true><<<gblocks, 256, 0, stream>>>(
        (const void*)h1, Wt2, dinv, g2, N_NODES);
    agg2_lsm_kernel<<<(N_NODES + 3) / 4, 256, 0, stream>>>(
        g2, row_ptr, csr_src, dinv, b2, out);
}